// Round 6
// baseline (1134.838 us; speedup 1.0000x reference)
//
#include <hip/hip_runtime.h>
#include <math.h>

#define NN 8192
#define L2E 1.44269504088896340736f
#define TWO_PI 6.28318530717958647693f

typedef _Float16 h8 __attribute__((ext_vector_type(8)));
typedef float f32x4 __attribute__((ext_vector_type(4)));
#define MFMA16(A, B, C) __builtin_amdgcn_mfma_f32_16x16x32_f16(A, B, C, 0, 0, 0)

// async 16B-per-lane global->LDS DMA; LDS dest is wave-uniform base + lane*16
#define GLD_LDS16(gsrc, ldst)                                          \
  __builtin_amdgcn_global_load_lds(                                    \
      (const __attribute__((address_space(1))) unsigned int*)(gsrc),   \
      (__attribute__((address_space(3))) unsigned int*)(ldst), 16, 0, 0)

union V8 { float4 v[2]; float f[8]; };

// Software grid barrier. Safe because grid == exact co-resident capacity
// (1024 blocks at 4/CU: LDS 33792*4 = 132K <= 160K, VGPR capped 128 by
// launch_bounds, 16 waves/CU <= 32). Distinct counter per phase.
__device__ __forceinline__ void grid_barrier(unsigned* bar, unsigned goal) {
  __syncthreads();
  if (threadIdx.x == 0) {
    __threadfence();  // release our block's writes to device scope
    __hip_atomic_fetch_add(bar, 1u, __ATOMIC_ACQ_REL, __HIP_MEMORY_SCOPE_AGENT);
    while (__hip_atomic_load(bar, __ATOMIC_ACQUIRE, __HIP_MEMORY_SCOPE_AGENT) <
           goal)
      __builtin_amdgcn_s_sleep(4);
  }
  __syncthreads();
  __threadfence();  // acquire: invalidate L1 so phase N+1 sees fresh data
}

// ---------------------------------------------------------------------------
// attn phase (R5's proven kernel body, smem passed in).
// 32 i-rows/block, 4-way j-split: tile=bid>>2, part=bid&3. 16 stages of 128 j
// staged via global_load_lds into double-buffered XOR-swizzled LDS.
// ---------------------------------------------------------------------------
template <bool NEED_L>
__device__ __forceinline__ void attn_phase(
    const float* __restrict__ eta_s, const float* __restrict__ phi_s,
    const _Float16* __restrict__ HT, float* __restrict__ Ypart,
    float* __restrict__ lpart, char* smem, float sc)
{
  _Float16* stage = (_Float16*)smem;  // 2 x 16384 B
  const int tid = threadIdx.x;
  const int w = tid >> 6, lane = tid & 63, m = lane & 15, g = lane >> 4;
  const int tile = blockIdx.x >> 2, part = blockIdx.x & 3;
  const int i0 = tile << 5;
  const int jbase = part << 11;
  const float Cs = TWO_PI * sc;
  const float et0 = eta_s[i0 + m],      ph0 = phi_s[i0 + m];
  const float et1 = eta_s[i0 + 16 + m], ph1 = phi_s[i0 + 16 + m];

  const int r0 = tid >> 4, gq = tid & 15;
  const _Float16* sbase = HT + (size_t)r0 * NN + ((gq ^ r0) << 3) + jbase;

  f32x4 a00 = {0,0,0,0}, a01 = {0,0,0,0}, a02 = {0,0,0,0}, a03 = {0,0,0,0};
  f32x4 a10 = {0,0,0,0}, a11 = {0,0,0,0}, a12 = {0,0,0,0}, a13 = {0,0,0,0};
  float l0 = 0.f, l1 = 0.f;

  const float* ep = eta_s + jbase + (w << 5) + (g << 3);
  const float* pp = phi_s + jbase + (w << 5) + (g << 3);
  V8 E, P, En, Pn;
  E.v[0] = *(const float4*)ep;  E.v[1] = *(const float4*)(ep + 4);
  P.v[0] = *(const float4*)pp;  P.v[1] = *(const float4*)(pp + 4);
  En = E; Pn = P;

#pragma unroll
  for (int k = 0; k < 4; ++k)
    GLD_LDS16(sbase + (size_t)k * 16 * NN, stage + ((k * 256 + tid) << 3));
  __syncthreads();

  const int fs = ((m << 4) + (((w << 2) | g) ^ m)) << 3;
  union AF { h8 v; decltype(__builtin_amdgcn_cvt_pkrtz(0.f, 0.f)) p[4]; };

  for (int s = 0; s < 16; ++s) {
    _Float16* cur = stage + ((s & 1) << 13);
    if (s < 15) {
      _Float16* nxt = stage + (((s + 1) & 1) << 13);
      const _Float16* srcp = sbase + (s + 1) * 128;
#pragma unroll
      for (int k = 0; k < 4; ++k)
        GLD_LDS16(srcp + (size_t)k * 16 * NN, nxt + ((k * 256 + tid) << 3));
      En.v[0] = *(const float4*)(ep + 128); En.v[1] = *(const float4*)(ep + 132);
      Pn.v[0] = *(const float4*)(pp + 128); Pn.v[1] = *(const float4*)(pp + 132);
      ep += 128; pp += 128;
    }
    const h8 b0 = *(const h8*)(cur + fs);
    const h8 b1 = *(const h8*)(cur + 2048 + fs);
    const h8 b2 = *(const h8*)(cur + 4096 + fs);
    const h8 b3 = *(const h8*)(cur + 6144 + fs);

    AF af0, af1;
#pragma unroll
    for (int tt = 0; tt < 8; tt += 2) {
      float Pv[4];
#pragma unroll
      for (int u = 0; u < 2; ++u) {
        {
          const float dp = ph0 - P.f[tt + u];
          const float ad = fabsf(dp);
          const float wr = fminf(ad, Cs - ad);
          const float de = et0 - E.f[tt + u];
          const float r2 = fmaf(de, de, wr * wr);
          const float a  = __builtin_amdgcn_exp2f(-r2);
          const float pv = __builtin_amdgcn_exp2f(fmaf(a, L2E, -L2E));
          if constexpr (NEED_L) l0 += pv;
          Pv[u] = pv;
        }
        {
          const float dp = ph1 - P.f[tt + u];
          const float ad = fabsf(dp);
          const float wr = fminf(ad, Cs - ad);
          const float de = et1 - E.f[tt + u];
          const float r2 = fmaf(de, de, wr * wr);
          const float a  = __builtin_amdgcn_exp2f(-r2);
          const float pv = __builtin_amdgcn_exp2f(fmaf(a, L2E, -L2E));
          if constexpr (NEED_L) l1 += pv;
          Pv[2 + u] = pv;
        }
      }
      af0.p[tt >> 1] = __builtin_amdgcn_cvt_pkrtz(Pv[0], Pv[1]);
      af1.p[tt >> 1] = __builtin_amdgcn_cvt_pkrtz(Pv[2], Pv[3]);
    }
    a00 = MFMA16(af0.v, b0, a00); a01 = MFMA16(af0.v, b1, a01);
    a02 = MFMA16(af0.v, b2, a02); a03 = MFMA16(af0.v, b3, a03);
    a10 = MFMA16(af1.v, b0, a10); a11 = MFMA16(af1.v, b1, a11);
    a12 = MFMA16(af1.v, b2, a12); a13 = MFMA16(af1.v, b3, a13);
    E = En; P = Pn;
    __syncthreads();
  }

  // cross-wave reduction. D layout: col=lane&15, row=(lane>>4)*4+reg.
  typedef float Red2[32][66];
  Red2* red = (Red2*)smem;
  float* lredF = (float*)(smem + 32768);
  const int h = w >> 1;
  if ((w & 1) == 0) {
#pragma unroll
    for (int r = 0; r < 4; ++r) {
      red[h][g * 4 + r][m]      = a00[r]; red[h][g * 4 + r][16 + m] = a01[r];
      red[h][g * 4 + r][32 + m] = a02[r]; red[h][g * 4 + r][48 + m] = a03[r];
      red[h][16 + g * 4 + r][m]      = a10[r]; red[h][16 + g * 4 + r][16 + m] = a11[r];
      red[h][16 + g * 4 + r][32 + m] = a12[r]; red[h][16 + g * 4 + r][48 + m] = a13[r];
    }
    if constexpr (NEED_L) {
      lredF[h * 128 + g * 32 + m] = l0; lredF[h * 128 + g * 32 + 16 + m] = l1;
    }
  }
  __syncthreads();
  if (w & 1) {
#pragma unroll
    for (int r = 0; r < 4; ++r) {
      red[h][g * 4 + r][m]      += a00[r]; red[h][g * 4 + r][16 + m] += a01[r];
      red[h][g * 4 + r][32 + m] += a02[r]; red[h][g * 4 + r][48 + m] += a03[r];
      red[h][16 + g * 4 + r][m]      += a10[r]; red[h][16 + g * 4 + r][16 + m] += a11[r];
      red[h][16 + g * 4 + r][32 + m] += a12[r]; red[h][16 + g * 4 + r][48 + m] += a13[r];
    }
    if constexpr (NEED_L) {
      lredF[h * 128 + g * 32 + m] += l0; lredF[h * 128 + g * 32 + 16 + m] += l1;
    }
  }
  __syncthreads();
#pragma unroll
  for (int k = 0; k < 8; ++k) {
    const int e = tid + k * 256;
    Ypart[((size_t)part * NN + i0 + (e >> 6)) * 64 + (e & 63)] =
        red[0][e >> 6][e & 63] + red[1][e >> 6][e & 63];
  }
  if constexpr (NEED_L) {
    if (tid < 32) {
      float sv = 0.f;
#pragma unroll
      for (int hh = 0; hh < 2; ++hh)
#pragma unroll
        for (int gg = 0; gg < 4; ++gg) sv += lredF[hh * 128 + gg * 32 + tid];
      lpart[(size_t)part * NN + i0 + tid] = sv;
    }
  }
}

// ---------------------------------------------------------------------------
// Fused mega-kernel: prep -> attn1 -> mid -> attn2 -> final -> out with
// software grid barriers. Grid 1024 x 256 = exact co-resident capacity.
// ---------------------------------------------------------------------------
__global__ __launch_bounds__(256, 4) void mega(
    const float* __restrict__ x, const float* __restrict__ alpha,
    const float* __restrict__ W1, const float* __restrict__ b1,
    const float* __restrict__ wt1, const float* __restrict__ bs1,
    const float* __restrict__ W2, const float* __restrict__ b2,
    const float* __restrict__ wt2, const float* __restrict__ bs2,
    const float* __restrict__ Wl, const float* __restrict__ bl,
    float* __restrict__ eta_s, float* __restrict__ phi_s,
    float* __restrict__ H1, float* __restrict__ H2,
    _Float16* __restrict__ HT, float* __restrict__ Ypart,
    float* __restrict__ lpart, float* __restrict__ svec,
    unsigned* __restrict__ bar, float* __restrict__ out)
{
  __shared__ __align__(16) char smem[33792];
  const int tid = threadIdx.x;
  const int bid = blockIdx.x;
  const unsigned NB = gridDim.x;
  const float sc = sqrtf(alpha[0] * L2E);

  // ---- P0: prep (8 rows/block): H1 = relu(x@W1+b1), eta/phi pre-scale ----
  {
    float* T = (float*)smem;  // [8][65]
    if (bid == 0 && tid < 64) svec[tid] = 0.f;
    const int i0 = bid * 8;
    const int r = tid >> 5, c = tid & 31;
    const int i = i0 + r;
    float xv[7];
#pragma unroll
    for (int k = 0; k < 7; k++) xv[k] = x[i * 7 + k];
    if (c == 0) { eta_s[i] = xv[1] * sc; phi_s[i] = xv[2] * sc; }
    for (int cc = c; cc < 64; cc += 32) {
      float hv = b1[cc];
#pragma unroll
      for (int k = 0; k < 7; k++) hv = fmaf(xv[k], W1[k * 64 + cc], hv);
      hv = fmaxf(hv, 0.f);
      H1[(size_t)i * 64 + cc] = hv;
      T[r * 65 + cc] = hv;
    }
    __syncthreads();
    const int n = tid >> 2, ri = (tid & 3) * 2;
    union { _Float16 hh[2]; unsigned u; } pk;
    pk.hh[0] = (_Float16)T[ri * 65 + n];
    pk.hh[1] = (_Float16)T[(ri + 1) * 65 + n];
    *(unsigned*)(HT + (size_t)n * NN + i0 + ri) = pk.u;
  }
  grid_barrier(bar + 0, NB);

  // ---- P1: attention pass 1 ----
  attn_phase<true>(eta_s, phi_s, HT, Ypart, lpart, smem, sc);
  grid_barrier(bar + 1, NB);

  // ---- P2: mid (8 rows/block) ----
  {
    const int i0 = bid * 8;
    const int r = tid >> 5, c = tid & 31;
    const int i = i0 + r;
    const float l = lpart[i] + lpart[NN + i] + lpart[2 * NN + i] + lpart[3 * NN + i];
    const float rl = 1.0f / l;
    float* U = (float*)smem;            // [8][65]
    float* Z = (float*)smem + 8 * 65;   // [8][65]
    for (int cc = c; cc < 64; cc += 32) {
      const float y = Ypart[((size_t)0 * NN + i) * 64 + cc] +
                      Ypart[((size_t)1 * NN + i) * 64 + cc] +
                      Ypart[((size_t)2 * NN + i) * 64 + cc] +
                      Ypart[((size_t)3 * NN + i) * 64 + cc];
      U[r * 65 + cc] = fmaf(y, rl, H1[(size_t)i * 64 + cc]);
    }
    __syncthreads();
    const float bv1 = bs1[0];
    for (int cc = c; cc < 64; cc += 32) {
      float z = bv1;
#pragma unroll
      for (int k = 0; k < 64; ++k) z = fmaf(U[r * 65 + k], wt1[k * 64 + cc], z);
      Z[r * 65 + cc] = fmaxf(z, 0.f);
    }
    __syncthreads();
    for (int cc = c; cc < 64; cc += 32) {
      float hv = b2[cc];
#pragma unroll
      for (int k = 0; k < 64; ++k) hv = fmaf(Z[r * 65 + k], W2[k * 64 + cc], hv);
      hv = fmaxf(hv, 0.f);
      H2[(size_t)i * 64 + cc] = hv;
      U[r * 65 + cc] = hv;
    }
    __syncthreads();
    const int n = tid >> 2, ri = (tid & 3) * 2;
    union { _Float16 hh[2]; unsigned u; } pk;
    pk.hh[0] = (_Float16)U[ri * 65 + n];
    pk.hh[1] = (_Float16)U[(ri + 1) * 65 + n];
    *(unsigned*)(HT + (size_t)n * NN + i0 + ri) = pk.u;
  }
  grid_barrier(bar + 2, NB);

  // ---- P3: attention pass 2 ----
  attn_phase<false>(eta_s, phi_s, HT, Ypart, nullptr, smem, sc);
  grid_barrier(bar + 3, NB);

  // ---- P4: final (8 rows/block) ----
  {
    const int i0 = bid * 8;
    const int r = tid >> 5, c = tid & 31;
    const int i = i0 + r;
    const float l = lpart[i] + lpart[NN + i] + lpart[2 * NN + i] + lpart[3 * NN + i];
    const float rl = 1.0f / l;
    float* U = (float*)smem;
    float* V = (float*)smem + 8 * 65;
    for (int cc = c; cc < 64; cc += 32) {
      const float y = Ypart[((size_t)0 * NN + i) * 64 + cc] +
                      Ypart[((size_t)1 * NN + i) * 64 + cc] +
                      Ypart[((size_t)2 * NN + i) * 64 + cc] +
                      Ypart[((size_t)3 * NN + i) * 64 + cc];
      U[r * 65 + cc] = fmaf(y, rl, H2[(size_t)i * 64 + cc]);
    }
    __syncthreads();
    const float bv2 = bs2[0];
    for (int cc = c; cc < 64; cc += 32) {
      float z = bv2;
#pragma unroll
      for (int k = 0; k < 64; ++k) z = fmaf(U[r * 65 + k], wt2[k * 64 + cc], z);
      V[r * 65 + cc] = fmaxf(z, 0.f);
    }
    __syncthreads();
    if (tid < 64) {
      float ssum = 0.f;
#pragma unroll
      for (int rr = 0; rr < 8; ++rr) ssum += V[rr * 65 + tid];
      atomicAdd(svec + tid, ssum);
    }
  }
  grid_barrier(bar + 4, NB);

  // ---- P5: out ----
  if (bid == 0 && tid < 64) {
    float v = svec[tid] * Wl[tid];
#pragma unroll
    for (int off = 32; off > 0; off >>= 1) v += __shfl_down(v, off);
    if (tid == 0) {
      const float logit = v + bl[0];
      out[0] = 1.0f / (1.0f + __builtin_amdgcn_exp2f(-logit * L2E));
    }
  }
}

extern "C" void kernel_launch(void* const* d_in, const int* in_sizes, int n_in,
                              void* d_out, int out_size, void* d_ws,
                              size_t ws_size, hipStream_t stream)
{
  const float* x     = (const float*)d_in[0];
  const float* alpha = (const float*)d_in[1];
  const float* W1    = (const float*)d_in[2];
  const float* b1    = (const float*)d_in[3];
  const float* wt1   = (const float*)d_in[4];
  const float* bs1   = (const float*)d_in[5];
  const float* W2    = (const float*)d_in[6];
  const float* b2    = (const float*)d_in[7];
  const float* wt2   = (const float*)d_in[8];
  const float* bs2   = (const float*)d_in[9];
  const float* Wl    = (const float*)d_in[10];
  const float* bl    = (const float*)d_in[11];
  float* out = (float*)d_out;

  char* ws = (char*)d_ws;
  size_t off = 0;
  auto alloc = [&](size_t bytes) {
    void* p = ws + off;
    off = (off + bytes + 255) & ~(size_t)255;
    return p;
  };
  float* eta_s   = (float*)alloc(NN * 4 + 256);
  float* phi_s   = (float*)alloc(NN * 4 + 256);
  float* H1      = (float*)alloc((size_t)NN * 64 * 4);
  float* H2      = (float*)alloc((size_t)NN * 64 * 4);
  float* Ypart   = (float*)alloc((size_t)4 * NN * 64 * 4);   // 8 MB
  float* lpart   = (float*)alloc((size_t)4 * NN * 4);
  _Float16* HT   = (_Float16*)alloc((size_t)NN * 64 * 2 + 512);
  float* svec    = (float*)alloc(64 * 4);
  unsigned* bar  = (unsigned*)alloc(256);

  hipMemsetAsync(bar, 0, 256, stream);
  mega<<<1024, 256, 0, stream>>>(x, alpha, W1, b1, wt1, bs1, W2, b2, wt2, bs2,
                                 Wl, bl, eta_s, phi_s, H1, H2, HT, Ypart,
                                 lpart, svec, bar, out);
}

// Round 7
// 597.065 us; speedup vs baseline: 1.9007x; 1.9007x over previous
//
#include <hip/hip_runtime.h>
#include <math.h>

#define NN 8192
#define L2E 1.44269504088896340736f
#define TWO_PI 6.28318530717958647693f

typedef _Float16 h8 __attribute__((ext_vector_type(8)));
typedef float f32x4 __attribute__((ext_vector_type(4)));
#define MFMA16(A, B, C) __builtin_amdgcn_mfma_f32_16x16x32_f16(A, B, C, 0, 0, 0)

// async 16B-per-lane global->LDS DMA; LDS dest is wave-uniform base + lane*16
#define GLD_LDS16(gsrc, ldst)                                          \
  __builtin_amdgcn_global_load_lds(                                    \
      (const __attribute__((address_space(1))) unsigned int*)(gsrc),   \
      (__attribute__((address_space(3))) unsigned int*)(ldst), 16, 0, 0)

union V8 { float4 v[2]; float f[8]; };

// Lean software grid barrier. Grid == exact co-resident capacity (R6 proved
// no-deadlock at 1024 blocks / 4 per CU). Poll is RELAXED (agent-scope load:
// L1-bypassing but NO per-iteration cache maintenance — R6's ACQUIRE poll
// emitted buffer_inv every iteration and cost ~200us/barrier). One acquire
// fence after the condition trips.
__device__ __forceinline__ void grid_barrier(unsigned* ctr, unsigned goal) {
  __syncthreads();  // drains all waves' stores (vmcnt 0) before release
  if (threadIdx.x == 0) {
    __hip_atomic_fetch_add(ctr, 1u, __ATOMIC_RELEASE, __HIP_MEMORY_SCOPE_AGENT);
    while (__hip_atomic_load(ctr, __ATOMIC_RELAXED, __HIP_MEMORY_SCOPE_AGENT) <
           goal)
      __builtin_amdgcn_s_sleep(8);
    __builtin_amdgcn_fence(__ATOMIC_ACQUIRE, "agent");  // one L1/L2 inv
  }
  __syncthreads();
}

// ---------------------------------------------------------------------------
// attn phase (R5's proven body, unchanged).
// 32 i-rows/block, 4-way j-split: tile=bid>>2, part=bid&3. 16 stages of 128 j
// staged via global_load_lds into double-buffered XOR-swizzled LDS.
// ---------------------------------------------------------------------------
template <bool NEED_L>
__device__ __forceinline__ void attn_phase(
    const float* __restrict__ eta_s, const float* __restrict__ phi_s,
    const _Float16* __restrict__ HT, float* __restrict__ Ypart,
    float* __restrict__ lpart, char* smem, float sc)
{
  _Float16* stage = (_Float16*)smem;  // 2 x 16384 B
  const int tid = threadIdx.x;
  const int w = tid >> 6, lane = tid & 63, m = lane & 15, g = lane >> 4;
  const int tile = blockIdx.x >> 2, part = blockIdx.x & 3;
  const int i0 = tile << 5;
  const int jbase = part << 11;
  const float Cs = TWO_PI * sc;
  const float et0 = eta_s[i0 + m],      ph0 = phi_s[i0 + m];
  const float et1 = eta_s[i0 + 16 + m], ph1 = phi_s[i0 + 16 + m];

  const int r0 = tid >> 4, gq = tid & 15;
  const _Float16* sbase = HT + (size_t)r0 * NN + ((gq ^ r0) << 3) + jbase;

  f32x4 a00 = {0,0,0,0}, a01 = {0,0,0,0}, a02 = {0,0,0,0}, a03 = {0,0,0,0};
  f32x4 a10 = {0,0,0,0}, a11 = {0,0,0,0}, a12 = {0,0,0,0}, a13 = {0,0,0,0};
  float l0 = 0.f, l1 = 0.f;

  const float* ep = eta_s + jbase + (w << 5) + (g << 3);
  const float* pp = phi_s + jbase + (w << 5) + (g << 3);
  V8 E, P, En, Pn;
  E.v[0] = *(const float4*)ep;  E.v[1] = *(const float4*)(ep + 4);
  P.v[0] = *(const float4*)pp;  P.v[1] = *(const float4*)(pp + 4);
  En = E; Pn = P;

#pragma unroll
  for (int k = 0; k < 4; ++k)
    GLD_LDS16(sbase + (size_t)k * 16 * NN, stage + ((k * 256 + tid) << 3));
  __syncthreads();

  const int fs = ((m << 4) + (((w << 2) | g) ^ m)) << 3;
  union AF { h8 v; decltype(__builtin_amdgcn_cvt_pkrtz(0.f, 0.f)) p[4]; };

  for (int s = 0; s < 16; ++s) {
    _Float16* cur = stage + ((s & 1) << 13);
    if (s < 15) {
      _Float16* nxt = stage + (((s + 1) & 1) << 13);
      const _Float16* srcp = sbase + (s + 1) * 128;
#pragma unroll
      for (int k = 0; k < 4; ++k)
        GLD_LDS16(srcp + (size_t)k * 16 * NN, nxt + ((k * 256 + tid) << 3));
      En.v[0] = *(const float4*)(ep + 128); En.v[1] = *(const float4*)(ep + 132);
      Pn.v[0] = *(const float4*)(pp + 128); Pn.v[1] = *(const float4*)(pp + 132);
      ep += 128; pp += 128;
    }
    const h8 b0 = *(const h8*)(cur + fs);
    const h8 b1 = *(const h8*)(cur + 2048 + fs);
    const h8 b2 = *(const h8*)(cur + 4096 + fs);
    const h8 b3 = *(const h8*)(cur + 6144 + fs);

    AF af0, af1;
#pragma unroll
    for (int tt = 0; tt < 8; tt += 2) {
      float Pv[4];
#pragma unroll
      for (int u = 0; u < 2; ++u) {
        {
          const float dp = ph0 - P.f[tt + u];
          const float ad = fabsf(dp);
          const float wr = fminf(ad, Cs - ad);
          const float de = et0 - E.f[tt + u];
          const float r2 = fmaf(de, de, wr * wr);
          const float a  = __builtin_amdgcn_exp2f(-r2);
          const float pv = __builtin_amdgcn_exp2f(fmaf(a, L2E, -L2E));
          if constexpr (NEED_L) l0 += pv;
          Pv[u] = pv;
        }
        {
          const float dp = ph1 - P.f[tt + u];
          const float ad = fabsf(dp);
          const float wr = fminf(ad, Cs - ad);
          const float de = et1 - E.f[tt + u];
          const float r2 = fmaf(de, de, wr * wr);
          const float a  = __builtin_amdgcn_exp2f(-r2);
          const float pv = __builtin_amdgcn_exp2f(fmaf(a, L2E, -L2E));
          if constexpr (NEED_L) l1 += pv;
          Pv[2 + u] = pv;
        }
      }
      af0.p[tt >> 1] = __builtin_amdgcn_cvt_pkrtz(Pv[0], Pv[1]);
      af1.p[tt >> 1] = __builtin_amdgcn_cvt_pkrtz(Pv[2], Pv[3]);
    }
    a00 = MFMA16(af0.v, b0, a00); a01 = MFMA16(af0.v, b1, a01);
    a02 = MFMA16(af0.v, b2, a02); a03 = MFMA16(af0.v, b3, a03);
    a10 = MFMA16(af1.v, b0, a10); a11 = MFMA16(af1.v, b1, a11);
    a12 = MFMA16(af1.v, b2, a12); a13 = MFMA16(af1.v, b3, a13);
    E = En; P = Pn;
    __syncthreads();
  }

  // cross-wave reduction. D layout: col=lane&15, row=(lane>>4)*4+reg.
  typedef float Red2[32][66];
  Red2* red = (Red2*)smem;
  float* lredF = (float*)(smem + 32768);
  const int h = w >> 1;
  if ((w & 1) == 0) {
#pragma unroll
    for (int r = 0; r < 4; ++r) {
      red[h][g * 4 + r][m]      = a00[r]; red[h][g * 4 + r][16 + m] = a01[r];
      red[h][g * 4 + r][32 + m] = a02[r]; red[h][g * 4 + r][48 + m] = a03[r];
      red[h][16 + g * 4 + r][m]      = a10[r]; red[h][16 + g * 4 + r][16 + m] = a11[r];
      red[h][16 + g * 4 + r][32 + m] = a12[r]; red[h][16 + g * 4 + r][48 + m] = a13[r];
    }
    if constexpr (NEED_L) {
      lredF[h * 128 + g * 32 + m] = l0; lredF[h * 128 + g * 32 + 16 + m] = l1;
    }
  }
  __syncthreads();
  if (w & 1) {
#pragma unroll
    for (int r = 0; r < 4; ++r) {
      red[h][g * 4 + r][m]      += a00[r]; red[h][g * 4 + r][16 + m] += a01[r];
      red[h][g * 4 + r][32 + m] += a02[r]; red[h][g * 4 + r][48 + m] += a03[r];
      red[h][16 + g * 4 + r][m]      += a10[r]; red[h][16 + g * 4 + r][16 + m] += a11[r];
      red[h][16 + g * 4 + r][32 + m] += a12[r]; red[h][16 + g * 4 + r][48 + m] += a13[r];
    }
    if constexpr (NEED_L) {
      lredF[h * 128 + g * 32 + m] += l0; lredF[h * 128 + g * 32 + 16 + m] += l1;
    }
  }
  __syncthreads();
#pragma unroll
  for (int k = 0; k < 8; ++k) {
    const int e = tid + k * 256;
    Ypart[((size_t)part * NN + i0 + (e >> 6)) * 64 + (e & 63)] =
        red[0][e >> 6][e & 63] + red[1][e >> 6][e & 63];
  }
  if constexpr (NEED_L) {
    if (tid < 32) {
      float sv = 0.f;
#pragma unroll
      for (int hh = 0; hh < 2; ++hh)
#pragma unroll
        for (int gg = 0; gg < 4; ++gg) sv += lredF[hh * 128 + gg * 32 + tid];
      lpart[(size_t)part * NN + i0 + tid] = sv;
    }
  }
}

// ---------------------------------------------------------------------------
// Fused mega-kernel with lean barriers. Grid 1024 x 256 = exact capacity.
// ---------------------------------------------------------------------------
__global__ __launch_bounds__(256, 4) void mega(
    const float* __restrict__ x, const float* __restrict__ alpha,
    const float* __restrict__ W1, const float* __restrict__ b1,
    const float* __restrict__ wt1, const float* __restrict__ bs1,
    const float* __restrict__ W2, const float* __restrict__ b2,
    const float* __restrict__ wt2, const float* __restrict__ bs2,
    const float* __restrict__ Wl, const float* __restrict__ bl,
    float* __restrict__ eta_s, float* __restrict__ phi_s,
    float* __restrict__ H1, float* __restrict__ H2,
    _Float16* __restrict__ HT, float* __restrict__ Ypart,
    float* __restrict__ lpart, float* __restrict__ svec,
    unsigned* __restrict__ bar, float* __restrict__ out)
{
  __shared__ __align__(16) char smem[33792];
  const int tid = threadIdx.x;
  const int bid = blockIdx.x;
  const unsigned NB = gridDim.x;
  const float sc = sqrtf(alpha[0] * L2E);

  // ---- P0: prep (8 rows/block): H1 = relu(x@W1+b1), eta/phi pre-scale ----
  {
    float* T = (float*)smem;  // [8][65]
    if (bid == 0 && tid < 64) svec[tid] = 0.f;
    const int i0 = bid * 8;
    const int r = tid >> 5, c = tid & 31;
    const int i = i0 + r;
    float xv[7];
#pragma unroll
    for (int k = 0; k < 7; k++) xv[k] = x[i * 7 + k];
    if (c == 0) { eta_s[i] = xv[1] * sc; phi_s[i] = xv[2] * sc; }
    for (int cc = c; cc < 64; cc += 32) {
      float hv = b1[cc];
#pragma unroll
      for (int k = 0; k < 7; k++) hv = fmaf(xv[k], W1[k * 64 + cc], hv);
      hv = fmaxf(hv, 0.f);
      H1[(size_t)i * 64 + cc] = hv;
      T[r * 65 + cc] = hv;
    }
    __syncthreads();
    const int n = tid >> 2, ri = (tid & 3) * 2;
    union { _Float16 hh[2]; unsigned u; } pk;
    pk.hh[0] = (_Float16)T[ri * 65 + n];
    pk.hh[1] = (_Float16)T[(ri + 1) * 65 + n];
    *(unsigned*)(HT + (size_t)n * NN + i0 + ri) = pk.u;
  }
  grid_barrier(bar + 0, NB);

  // ---- P1: attention pass 1 ----
  attn_phase<true>(eta_s, phi_s, HT, Ypart, lpart, smem, sc);
  grid_barrier(bar + 16, NB);

  // ---- P2: mid (8 rows/block) ----
  {
    const int i0 = bid * 8;
    const int r = tid >> 5, c = tid & 31;
    const int i = i0 + r;
    const float l = lpart[i] + lpart[NN + i] + lpart[2 * NN + i] + lpart[3 * NN + i];
    const float rl = 1.0f / l;
    float* U = (float*)smem;            // [8][65]
    float* Z = (float*)smem + 8 * 65;   // [8][65]
    for (int cc = c; cc < 64; cc += 32) {
      const float y = Ypart[((size_t)0 * NN + i) * 64 + cc] +
                      Ypart[((size_t)1 * NN + i) * 64 + cc] +
                      Ypart[((size_t)2 * NN + i) * 64 + cc] +
                      Ypart[((size_t)3 * NN + i) * 64 + cc];
      U[r * 65 + cc] = fmaf(y, rl, H1[(size_t)i * 64 + cc]);
    }
    __syncthreads();
    const float bv1 = bs1[0];
    for (int cc = c; cc < 64; cc += 32) {
      float z = bv1;
#pragma unroll
      for (int k = 0; k < 64; ++k) z = fmaf(U[r * 65 + k], wt1[k * 64 + cc], z);
      Z[r * 65 + cc] = fmaxf(z, 0.f);
    }
    __syncthreads();
    for (int cc = c; cc < 64; cc += 32) {
      float hv = b2[cc];
#pragma unroll
      for (int k = 0; k < 64; ++k) hv = fmaf(Z[r * 65 + k], W2[k * 64 + cc], hv);
      hv = fmaxf(hv, 0.f);
      H2[(size_t)i * 64 + cc] = hv;
      U[r * 65 + cc] = hv;
    }
    __syncthreads();
    const int n = tid >> 2, ri = (tid & 3) * 2;
    union { _Float16 hh[2]; unsigned u; } pk;
    pk.hh[0] = (_Float16)U[ri * 65 + n];
    pk.hh[1] = (_Float16)U[(ri + 1) * 65 + n];
    *(unsigned*)(HT + (size_t)n * NN + i0 + ri) = pk.u;
  }
  grid_barrier(bar + 32, NB);

  // ---- P3: attention pass 2 ----
  attn_phase<false>(eta_s, phi_s, HT, Ypart, nullptr, smem, sc);
  grid_barrier(bar + 48, NB);

  // ---- P4: final (8 rows/block) + last-ticket block computes out ----
  {
    const int i0 = bid * 8;
    const int r = tid >> 5, c = tid & 31;
    const int i = i0 + r;
    const float l = lpart[i] + lpart[NN + i] + lpart[2 * NN + i] + lpart[3 * NN + i];
    const float rl = 1.0f / l;
    float* U = (float*)smem;
    float* V = (float*)smem + 8 * 65;
    for (int cc = c; cc < 64; cc += 32) {
      const float y = Ypart[((size_t)0 * NN + i) * 64 + cc] +
                      Ypart[((size_t)1 * NN + i) * 64 + cc] +
                      Ypart[((size_t)2 * NN + i) * 64 + cc] +
                      Ypart[((size_t)3 * NN + i) * 64 + cc];
      U[r * 65 + cc] = fmaf(y, rl, H2[(size_t)i * 64 + cc]);
    }
    __syncthreads();
    const float bv2 = bs2[0];
    for (int cc = c; cc < 64; cc += 32) {
      float z = bv2;
#pragma unroll
      for (int k = 0; k < 64; ++k) z = fmaf(U[r * 65 + k], wt2[k * 64 + cc], z);
      V[r * 65 + cc] = fmaxf(z, 0.f);
    }
    __syncthreads();
    if (tid < 64) {
      float ssum = 0.f;
#pragma unroll
      for (int rr = 0; rr < 8; ++rr) ssum += V[rr * 65 + tid];
      atomicAdd(svec + tid, ssum);
    }
    __syncthreads();
    // ticket: last block to finish P4 computes the output scalar
    __shared__ unsigned last;
    if (tid == 0)
      last = __hip_atomic_fetch_add(bar + 64, 1u, __ATOMIC_ACQ_REL,
                                    __HIP_MEMORY_SCOPE_AGENT);
    __syncthreads();
    if (last == NB - 1) {
      if (tid == 0) __builtin_amdgcn_fence(__ATOMIC_ACQUIRE, "agent");
      __syncthreads();
      if (tid < 64) {
        float v = svec[tid] * Wl[tid];
#pragma unroll
        for (int off = 32; off > 0; off >>= 1) v += __shfl_down(v, off);
        if (tid == 0) {
          const float logit = v + bl[0];
          out[0] = 1.0f / (1.0f + __builtin_amdgcn_exp2f(-logit * L2E));
        }
      }
    }
  }
}

extern "C" void kernel_launch(void* const* d_in, const int* in_sizes, int n_in,
                              void* d_out, int out_size, void* d_ws,
                              size_t ws_size, hipStream_t stream)
{
  const float* x     = (const float*)d_in[0];
  const float* alpha = (const float*)d_in[1];
  const float* W1    = (const float*)d_in[2];
  const float* b1    = (const float*)d_in[3];
  const float* wt1   = (const float*)d_in[4];
  const float* bs1   = (const float*)d_in[5];
  const float* W2    = (const float*)d_in[6];
  const float* b2    = (const float*)d_in[7];
  const float* wt2   = (const float*)d_in[8];
  const float* bs2   = (const float*)d_in[9];
  const float* Wl    = (const float*)d_in[10];
  const float* bl    = (const float*)d_in[11];
  float* out = (float*)d_out;

  char* ws = (char*)d_ws;
  size_t off = 0;
  auto alloc = [&](size_t bytes) {
    void* p = ws + off;
    off = (off + bytes + 255) & ~(size_t)255;
    return p;
  };
  float* eta_s   = (float*)alloc(NN * 4 + 256);
  float* phi_s   = (float*)alloc(NN * 4 + 256);
  float* H1      = (float*)alloc((size_t)NN * 64 * 4);
  float* H2      = (float*)alloc((size_t)NN * 64 * 4);
  float* Ypart   = (float*)alloc((size_t)4 * NN * 64 * 4);   // 8 MB
  float* lpart   = (float*)alloc((size_t)4 * NN * 4);
  _Float16* HT   = (_Float16*)alloc((size_t)NN * 64 * 2 + 512);
  float* svec    = (float*)alloc(64 * 4);
  unsigned* bar  = (unsigned*)alloc(512);   // counters spaced 64B apart

  hipMemsetAsync(bar, 0, 512, stream);
  mega<<<1024, 256, 0, stream>>>(x, alpha, W1, b1, wt1, bs1, W2, b2, wt2, bs2,
                                 Wl, bl, eta_s, phi_s, H1, H2, HT, Ypart,
                                 lpart, svec, bar, out);
}

// Round 8
// 189.905 us; speedup vs baseline: 5.9758x; 3.1440x over previous
//
#include <hip/hip_runtime.h>
#include <math.h>

#define NN 8192
#define L2E 1.44269504088896340736f
#define TWO_PI 6.28318530717958647693f

typedef _Float16 h8 __attribute__((ext_vector_type(8)));
typedef float f32x4 __attribute__((ext_vector_type(4)));
#define MFMA16(A, B, C) __builtin_amdgcn_mfma_f32_16x16x32_f16(A, B, C, 0, 0, 0)

// async 16B-per-lane global->LDS DMA; LDS dest is wave-uniform base + lane*16
#define GLD_LDS16(gsrc, ldst)                                          \
  __builtin_amdgcn_global_load_lds(                                    \
      (const __attribute__((address_space(1))) unsigned int*)(gsrc),   \
      (__attribute__((address_space(3))) unsigned int*)(ldst), 16, 0, 0)

union V8 { float4 v[2]; float f[8]; };
union AF { h8 v; decltype(__builtin_amdgcn_cvt_pkrtz(0.f, 0.f)) p[4]; };

// ---------------------------------------------------------------------------
// prep (R5 verbatim): eta_s=eta*s, phi_s=phi*s, s=sqrt(alpha*log2e);
// H1 = relu(x@W1+b1) f32 row-major + f16 transposed [64][NN]. 32 rows/block.
// ---------------------------------------------------------------------------
__global__ __launch_bounds__(256) void prep_kernel(
    const float* __restrict__ x, const float* __restrict__ alpha,
    const float* __restrict__ W1, const float* __restrict__ b1,
    float* __restrict__ eta_s, float* __restrict__ phi_s,
    float* __restrict__ H1, _Float16* __restrict__ HT1,
    float* __restrict__ svec)
{
  __shared__ float sW[448];
  __shared__ float sb[64];
  __shared__ float T[32][65];
  const int t = threadIdx.x;
  if (blockIdx.x == 0 && t < 64) svec[t] = 0.f;
  for (int k = t; k < 448; k += 256) sW[k] = W1[k];
  if (t < 64) sb[t] = b1[t];
  const float s = sqrtf(alpha[0] * L2E);
  const int i0 = blockIdx.x * 32;
  const int r = t >> 3, q = t & 7;
  const int i = i0 + r;
  float xv[7];
#pragma unroll
  for (int k = 0; k < 7; k++) xv[k] = x[i * 7 + k];
  if (q == 0) { eta_s[i] = xv[1] * s; phi_s[i] = xv[2] * s; }
  __syncthreads();
#pragma unroll
  for (int c = 0; c < 8; c++) {
    const int n = q * 8 + c;
    float hv = sb[n];
#pragma unroll
    for (int k = 0; k < 7; k++) hv = fmaf(xv[k], sW[k * 64 + n], hv);
    T[r][n] = fmaxf(hv, 0.f);
  }
  __syncthreads();
  for (int e = t; e < 2048; e += 256) H1[i0 * 64 + e] = T[e >> 6][e & 63];
  const int n = t >> 2, sg = (t & 3) * 8;
  h8 v;
#pragma unroll
  for (int ss = 0; ss < 8; ss++) v[ss] = (_Float16)T[sg + ss][n];
  *(h8*)(HT1 + (size_t)n * NN + i0 + sg) = v;
}

// ---------------------------------------------------------------------------
// fused_pass<1>: Y=P@H1 (full j in-block) -> U=Y/l+H1 -> Z=relu(U@wt1+bs1)
//                -> H2=relu(Z@W2+b2) -> write H2 f32 + HT2 f16-T + lsum.
// fused_pass<2>: Y=P@H2 -> U=Y/l+H2 -> V=relu(U@wt2+bs2) -> col-sum ->
//                atomicAdd svec; last-ticket block computes sigmoid out.
// Block: 512 thr = 8 waves; 16 i-rows/block, wave w covers j in w*1024..+1024
// via 32 block-stages of 256 j staged with global_load_lds (double-buffered,
// XOR-swizzled). Grid 512 = 2 blocks/CU.
// ---------------------------------------------------------------------------
template <int PASS>
__global__ __launch_bounds__(512, 4) void fused_pass(
    const float* __restrict__ eta_s, const float* __restrict__ phi_s,
    const _Float16* __restrict__ HTin, const float* __restrict__ Hres,
    const float* __restrict__ WA, const float* __restrict__ bsA,
    const float* __restrict__ WB, const float* __restrict__ bB,
    const float* __restrict__ alpha, float* __restrict__ lsum,
    float* __restrict__ Hout, _Float16* __restrict__ HTout,
    float* __restrict__ svec, const float* __restrict__ Wl,
    const float* __restrict__ bl, float* __restrict__ out,
    unsigned* __restrict__ bar)
{
  __shared__ __align__(16) char smem[65536];
  __shared__ unsigned last_ticket;
  _Float16* stage = (_Float16*)smem;  // 2 x 32768 B ([64 rows][256 j] f16)
  const int tid = threadIdx.x;
  const int w = tid >> 6, lane = tid & 63, m = lane & 15, g = lane >> 4;
  const int i0 = blockIdx.x << 4;
  const float Cs = TWO_PI * sqrtf(alpha[0] * L2E);
  const float et0 = eta_s[i0 + m], ph0 = phi_s[i0 + m];

  // staging: issue k (0..3), thread t -> slot d = k*512+t: row = d>>5,
  // stored j-group (of 8) = (d&31) ^ (row&31). LDS byte = d*16.
  const int rr = tid >> 5, gq = tid & 31;
  const _Float16* sb4[4];
#pragma unroll
  for (int k = 0; k < 4; ++k) {
    const int rowk = k * 16 + rr;
    sb4[k] = HTin + (size_t)rowk * NN + ((gq ^ (rowk & 31)) << 3);
  }
  // frag read offsets (f16 elems): c-th n-group: row=c*16+m,
  // slot = (w*4+g) ^ (row&31)
  int fo[4];
#pragma unroll
  for (int c = 0; c < 4; ++c) {
    const int row = c * 16 + m;
    fo[c] = row * 256 + ((((w << 2) | g) ^ (row & 31)) << 3);
  }

  f32x4 a0 = {0,0,0,0}, a1 = {0,0,0,0}, a2 = {0,0,0,0}, a3 = {0,0,0,0};
  float lacc = 0.f;

  // eta/phi: wave's slice of each stage: offset w*32 + g*8, +256/stage
  const float* ep = eta_s + (w << 5) + (g << 3);
  const float* pp = phi_s + (w << 5) + (g << 3);
  V8 E, P, En, Pn;
  E.v[0] = *(const float4*)ep;  E.v[1] = *(const float4*)(ep + 4);
  P.v[0] = *(const float4*)pp;  P.v[1] = *(const float4*)(pp + 4);
  En = E; Pn = P;

#pragma unroll
  for (int k = 0; k < 4; ++k)
    GLD_LDS16(sb4[k], stage + ((k * 512 + tid) << 3));
  __syncthreads();

  for (int s = 0; s < 32; ++s) {
    _Float16* cur = stage + ((s & 1) << 14);
    if (s < 31) {
      _Float16* nxt = stage + (((s + 1) & 1) << 14);
      const int joff = (s + 1) * 256;
#pragma unroll
      for (int k = 0; k < 4; ++k)
        GLD_LDS16(sb4[k] + joff, nxt + ((k * 512 + tid) << 3));
      ep += 256; pp += 256;
      En.v[0] = *(const float4*)ep;  En.v[1] = *(const float4*)(ep + 4);
      Pn.v[0] = *(const float4*)pp;  Pn.v[1] = *(const float4*)(pp + 4);
    }
    const h8 b0 = *(const h8*)(cur + fo[0]);
    const h8 b1 = *(const h8*)(cur + fo[1]);
    const h8 b2 = *(const h8*)(cur + fo[2]);
    const h8 b3 = *(const h8*)(cur + fo[3]);

    AF af;
#pragma unroll
    for (int tt = 0; tt < 8; tt += 2) {
      float Pv[2];
#pragma unroll
      for (int u = 0; u < 2; ++u) {
        const float dp = ph0 - P.f[tt + u];
        const float ad = fabsf(dp);
        const float wr = fminf(ad, Cs - ad);
        const float de = et0 - E.f[tt + u];
        const float r2 = fmaf(de, de, wr * wr);
        const float a  = __builtin_amdgcn_exp2f(-r2);
        const float pv = __builtin_amdgcn_exp2f(fmaf(a, L2E, -L2E));
        if constexpr (PASS == 1) lacc += pv;
        Pv[u] = pv;
      }
      af.p[tt >> 1] = __builtin_amdgcn_cvt_pkrtz(Pv[0], Pv[1]);
    }
    a0 = MFMA16(af.v, b0, a0); a1 = MFMA16(af.v, b1, a1);
    a2 = MFMA16(af.v, b2, a2); a3 = MFMA16(af.v, b3, a3);
    E = En; P = Pn;
    __syncthreads();  // drains DMA for s+1 and all frag reads of cur
  }

  // ---- epilogue: 8-wave Y reduction (arena overlays stage) ----
  float* RED  = (float*)smem;            // [8][16][68] = 34816 B
  float* LRED = (float*)(smem + 34816);  // [32][16]    = 2048 B
  float* LROW = (float*)(smem + 36864);  // [16]
  float* UBUF = (float*)(smem + 37120);  // [16][68]    = 4352 B
  float* ZBUF = (float*)(smem + 41728);  // [16][68]    = 4352 B

  // D layout: col = lane&15 (n within group c), row = g*4 + reg
#pragma unroll
  for (int r = 0; r < 4; ++r) {
    const int rowi = (w * 16 + g * 4 + r) * 68;
    RED[rowi + m]      = a0[r];
    RED[rowi + 16 + m] = a1[r];
    RED[rowi + 32 + m] = a2[r];
    RED[rowi + 48 + m] = a3[r];
  }
  if constexpr (PASS == 1) LRED[((w << 2) | g) * 16 + m] = lacc;
  __syncthreads();

  const int r  = tid >> 5;          // 0..15 (row)
  const int c2 = (tid & 31) << 1;   // 0..62 even (col pair)
  float y0 = 0.f, y1 = 0.f;
#pragma unroll
  for (int q = 0; q < 8; ++q) {
    y0 += RED[(q * 16 + r) * 68 + c2];
    y1 += RED[(q * 16 + r) * 68 + c2 + 1];
  }
  const float2 hres = *(const float2*)(Hres + (size_t)(i0 + r) * 64 + c2);
  if (tid < 16) {
    float lv;
    if constexpr (PASS == 1) {
      lv = 0.f;
#pragma unroll
      for (int q = 0; q < 32; ++q) lv += LRED[q * 16 + tid];
      lsum[i0 + tid] = lv;
    } else {
      lv = lsum[i0 + tid];
    }
    LROW[tid] = lv;
  }
  __syncthreads();

  const float rl = 1.0f / LROW[r];
  UBUF[r * 68 + c2]     = fmaf(y0, rl, hres.x);
  UBUF[r * 68 + c2 + 1] = fmaf(y1, rl, hres.y);
  __syncthreads();

  // Z = relu(U @ WA + bsA[0])
  float z0 = bsA[0], z1 = z0;
  for (int k = 0; k < 64; ++k) {
    const float uk = UBUF[r * 68 + k];
    const float2 wv = *(const float2*)(WA + k * 64 + c2);
    z0 = fmaf(uk, wv.x, z0);
    z1 = fmaf(uk, wv.y, z1);
  }
  z0 = fmaxf(z0, 0.f); z1 = fmaxf(z1, 0.f);
  ZBUF[r * 68 + c2]     = z0;
  ZBUF[r * 68 + c2 + 1] = z1;
  __syncthreads();

  if constexpr (PASS == 1) {
    // H2 = relu(Z @ WB + bB)
    float h0 = bB[c2], h1 = bB[c2 + 1];
    for (int k = 0; k < 64; ++k) {
      const float zk = ZBUF[r * 68 + k];
      const float2 wv = *(const float2*)(WB + k * 64 + c2);
      h0 = fmaf(zk, wv.x, h0);
      h1 = fmaf(zk, wv.y, h1);
    }
    h0 = fmaxf(h0, 0.f); h1 = fmaxf(h1, 0.f);
    float2 hw; hw.x = h0; hw.y = h1;
    *(float2*)(Hout + (size_t)(i0 + r) * 64 + c2) = hw;
    UBUF[r * 68 + c2]     = h0;   // safe: all UBUF reads ended before last sync
    UBUF[r * 68 + c2 + 1] = h1;
    __syncthreads();
    // HT2 f16 transposed: n = tid>>3 (0..63), ri = (tid&7)*2
    const int n = tid >> 3, ri = (tid & 7) << 1;
    union { _Float16 hh[2]; unsigned u; } pk;
    pk.hh[0] = (_Float16)UBUF[ri * 68 + n];
    pk.hh[1] = (_Float16)UBUF[(ri + 1) * 68 + n];
    *(unsigned*)(HTout + (size_t)n * NN + i0 + ri) = pk.u;
  } else {
    // V = Z (already relu'd); column sums -> svec
    if (tid < 64) {
      float cs = 0.f;
#pragma unroll
      for (int rw = 0; rw < 16; ++rw) cs += ZBUF[rw * 68 + tid];
      atomicAdd(svec + tid, cs);
    }
    __syncthreads();  // drains svec atomics (vmcnt) before ticket
    if (tid == 0)
      last_ticket = __hip_atomic_fetch_add(bar, 1u, __ATOMIC_RELAXED,
                                           __HIP_MEMORY_SCOPE_AGENT);
    __syncthreads();
    if (last_ticket == gridDim.x - 1) {
      if (tid == 0) __builtin_amdgcn_fence(__ATOMIC_ACQUIRE, "agent");
      __syncthreads();
      if (tid < 64) {
        float v = svec[tid] * Wl[tid];
#pragma unroll
        for (int off = 32; off > 0; off >>= 1) v += __shfl_down(v, off);
        if (tid == 0) {
          const float logit = v + bl[0];
          out[0] = 1.0f / (1.0f + __builtin_amdgcn_exp2f(-logit * L2E));
        }
      }
    }
  }
}

extern "C" void kernel_launch(void* const* d_in, const int* in_sizes, int n_in,
                              void* d_out, int out_size, void* d_ws,
                              size_t ws_size, hipStream_t stream)
{
  const float* x     = (const float*)d_in[0];
  const float* alpha = (const float*)d_in[1];
  const float* W1    = (const float*)d_in[2];
  const float* b1    = (const float*)d_in[3];
  const float* wt1   = (const float*)d_in[4];
  const float* bs1   = (const float*)d_in[5];
  const float* W2    = (const float*)d_in[6];
  const float* b2    = (const float*)d_in[7];
  const float* wt2   = (const float*)d_in[8];
  const float* bs2   = (const float*)d_in[9];
  const float* Wl    = (const float*)d_in[10];
  const float* bl    = (const float*)d_in[11];
  float* out = (float*)d_out;

  char* ws = (char*)d_ws;
  size_t off = 0;
  auto alloc = [&](size_t bytes) {
    void* p = ws + off;
    off = (off + bytes + 255) & ~(size_t)255;
    return p;
  };
  float* eta_s   = (float*)alloc(NN * 4 + 256);
  float* phi_s   = (float*)alloc(NN * 4 + 256);
  float* H1      = (float*)alloc((size_t)NN * 64 * 4);
  float* H2      = (float*)alloc((size_t)NN * 64 * 4);
  _Float16* HT1  = (_Float16*)alloc((size_t)NN * 64 * 2 + 512);
  _Float16* HT2  = (_Float16*)alloc((size_t)NN * 64 * 2 + 512);
  float* lsum    = (float*)alloc(NN * 4);
  float* svec    = (float*)alloc(64 * 4);
  unsigned* bar  = (unsigned*)alloc(256);

  hipMemsetAsync(bar, 0, 256, stream);
  prep_kernel<<<256, 256, 0, stream>>>(x, alpha, W1, b1, eta_s, phi_s, H1,
                                       HT1, svec);
  fused_pass<1><<<512, 512, 0, stream>>>(eta_s, phi_s, HT1, H1, wt1, bs1, W2,
                                         b2, alpha, lsum, H2, HT2, nullptr,
                                         nullptr, nullptr, nullptr, nullptr);
  fused_pass<2><<<512, 512, 0, stream>>>(eta_s, phi_s, HT2, H2, wt2, bs2,
                                         nullptr, nullptr, alpha, lsum,
                                         nullptr, nullptr, svec, Wl, bl, out,
                                         bar);
}